// Round 16
// baseline (2801.576 us; speedup 1.0000x reference)
//
#include <hip/hip_runtime.h>
#include <math.h>

// Griffin-Lim inversion, fused bf16-3-term MFMA, M-tile=32, half-folded
// (r13/r15 validated math, bit-identical values), S-CHUNK STREAMED:
// gemm1 keeps full X in registers; per 32-bin chunk kb the owning waves dump
// their acc slab to a small fp32 tr tile, 256 threads phase-modify+split3
// into a double-buffered 12 KB S-chunk, and all waves run gemm2's kc=kb
// partial.  LDS 66->45.3 KB => 3 blocks/CU (was 2).  gemm2 accumulates
// across kb in registers; unfold at the end.  Values identical to r15.

#define B_SZ 128
#define NFRM 256
#define BINS 128
#define NFFT 254
#define OUTL 16574
#define AUD  16384
#define GL_ITERS 50
#define MAXV 69.37411499023438f
#define PI2f 6.2831853071795864f

typedef __attribute__((ext_vector_type(8))) short short8;
typedef __attribute__((ext_vector_type(4))) short short4v;
typedef __attribute__((ext_vector_type(4))) float f32x4;

__device__ __forceinline__ unsigned short f2bf(float f) {     // RNE f32->bf16
  unsigned u = __float_as_uint(f);
  return (unsigned short)((u + 0x7FFFu + ((u >> 16) & 1u)) >> 16);
}
__device__ __forceinline__ float bf2f(unsigned short h) {
  return __uint_as_float(((unsigned)h) << 16);
}
__device__ __forceinline__ void split3(float v, short* h, short* m, short* l) {
  unsigned short hh = f2bf(v);
  float r1 = v - bf2f(hh);
  unsigned short mm = f2bf(r1);
  float r2 = r1 - bf2f(mm);
  *h = (short)hh; *m = (short)mm; *l = (short)f2bf(r2);
}

#define MFMA6(ACC, AH, AM, AL, BH, BM, BL)                                   \
  ACC = __builtin_amdgcn_mfma_f32_16x16x32_bf16(AH, BL, ACC, 0, 0, 0);       \
  ACC = __builtin_amdgcn_mfma_f32_16x16x32_bf16(AM, BM, ACC, 0, 0, 0);       \
  ACC = __builtin_amdgcn_mfma_f32_16x16x32_bf16(AL, BH, ACC, 0, 0, 0);       \
  ACC = __builtin_amdgcn_mfma_f32_16x16x32_bf16(AH, BM, ACC, 0, 0, 0);       \
  ACC = __builtin_amdgcn_mfma_f32_16x16x32_bf16(AM, BH, ACC, 0, 0, 0);       \
  ACC = __builtin_amdgcn_mfma_f32_16x16x32_bf16(AH, BH, ACC, 0, 0, 0);

// ---------------------------------------------------------------- tables ----
__global__ void tables_k(short* __restrict__ WfH, short* __restrict__ WfM,
                         short* __restrict__ WfL, short* __restrict__ CI,
                         short* __restrict__ SI, float* __restrict__ swin,
                         unsigned* __restrict__ gmax) {
  int tid = blockIdx.x * blockDim.x + threadIdx.x;
  if (tid == 0) *gmax = 0u;
  if (tid < 256) {
    float v = 0.f;
    if (tid < NFFT) {
      float wn = 0.5f - 0.5f * cosf(PI2f * (float)tid / (float)NFFT);
      float d = 0.f;
      int p = tid & 63;
      for (int q = 0; q < 4; ++q) {
        int nn = p + 64 * q;
        if (nn < NFFT) { float w = 0.5f - 0.5f * cosf(PI2f * (float)nn / (float)NFFT); d += w * w; }
      }
      v = wn / d;
    }
    swin[tid] = v;
  }
  if (tid < 65536) {
    int j = tid & 7, l = (tid >> 3) & 63, nt = (tid >> 9) & 15, kc = tid >> 13;
    int krow = kc * 32 + ((l >> 4) << 3) + j;        // sample n 0..255
    int ncol = (nt << 4) + (l & 15);                 // spec col 0..255
    float v1 = 0.f;
    if (krow < NFFT) {
      int kk = ncol >> 1;
      int m = (kk * krow) % NFFT;
      float ang = PI2f * (float)m / (float)NFFT;
      float wn = 0.5f - 0.5f * cosf(PI2f * (float)krow / (float)NFFT);
      v1 = wn * ((ncol & 1) ? -sinf(ang) : cosf(ang));
    }
    split3(v1, &WfH[tid], &WfM[tid], &WfL[tid]);
  }
  if (tid < 16384) {
    int j = tid & 7, l = (tid >> 3) & 63;
    int krow = (tid >> 12) * 32 + ((l >> 4) << 3) + j;   // bin k 0..127
    int ncol = (((tid >> 9) & 7) << 4) + (l & 15);       // sample n 0..127
    int m = (krow * ncol) % NFFT;
    float ang = PI2f * (float)m / (float)NFFT;
    float sc = ((krow == 0 || krow == BINS - 1) ? 1.f : 2.f) / (float)NFFT;
    split3(sc * cosf(ang), &CI[tid], &CI[16384 + tid], &CI[32768 + tid]);
    split3(-sc * sinf(ang), &SI[tid], &SI[16384 + tid], &SI[32768 + tid]);
  }
}

// ------------------------------------------------------------------- mag ----
__global__ void mag_k(const float* __restrict__ x, float* __restrict__ mag) {
  int i = blockIdx.x * 256 + threadIdx.x;          // 4194304 exact
  mag[i] = expf(5.f * (x[i] - 1.f)) * MAXV;
}

// ------------------------------------------------------ fused GL iteration --
// Block (XCD-swizzled) = (batch b, 32 frames from f0). 512 threads, 8 waves.
// LDS: wfs (13.4 KB) | tr 32x65 f32 (8.3 KB, stride 65 => conflict-free
// scalar access) | Sc 2 bufs x {H,M,L} x [32 rows][64 sh: re 0..31 | im 0..31]
// (24 KB, 8-slot XOR swizzle per row).  Total 45.3 KB -> 3 blocks/CU.
template <int FIRST>
__global__ __launch_bounds__(512) void iter_k(
    const float* __restrict__ FRsrc, float* __restrict__ FRdst,
    const float* __restrict__ mag, const float* __restrict__ swin,
    const short* __restrict__ WfH, const short* __restrict__ WfM,
    const short* __restrict__ WfL,
    const short* __restrict__ CI, const short* __restrict__ SI) {
  __shared__ __align__(16) short wfsB[6720];
  __shared__ __align__(16) float tr[2080];
  __shared__ __align__(16) short Sc[12288];
  short* wfsH = wfsB;
  short* wfsM = wfsB + 2240;
  short* wfsL = wfsB + 4480;

  int o = blockIdx.x;
  int blk = ((o & 7) << 7) + (o >> 3);             // bijective (1024 % 8 == 0)
  int b = blk >> 3, f0 = (blk & 7) << 5;
  int tid = threadIdx.x, lane = tid & 63, wv = tid >> 6;
  int fgl = b * NFRM + f0;

  f32x4 acc1[2][2];
  f32x4 aC[2], aS[2];
#pragma unroll
  for (int i = 0; i < 2; ++i) { aC[i] = (f32x4){0,0,0,0}; aS[i] = (f32x4){0,0,0,0}; }

  if (!FIRST) {
    const float* FRb = FRsrc + ((size_t)b << 16);
    // vectorized fused overlap-add -> split3 -> swizzled wfs (r15 exact)
    for (int i4 = tid; i4 < 560; i4 += 512) {
      int i = i4 << 2;
      int t = (f0 << 6) + i;
      int ft = t >> 6, cb = t & 63;
      float4 s = make_float4(0.f, 0.f, 0.f, 0.f);
#pragma unroll
      for (int d = 3; d >= 0; --d) {               // ascending f; extras exact 0
        int f = ft - d;
        if (f >= 0 && f <= 255) {
          float4 v = *(const float4*)&FRb[(f << 8) + cb + (d << 6)];
          s.x += v.x; s.y += v.y; s.z += v.z; s.w += v.w;
        }
      }
      if (i == 2236) { s.z = 0.f; s.w = 0.f; }     // pad samples 2238/2239
      short hh[4] __attribute__((aligned(8))), mm[4] __attribute__((aligned(8))),
            ll[4] __attribute__((aligned(8)));
      split3(s.x, &hh[0], &mm[0], &ll[0]);
      split3(s.y, &hh[1], &mm[1], &ll[1]);
      split3(s.z, &hh[2], &mm[2], &ll[2]);
      split3(s.w, &hh[3], &mm[3], &ll[3]);
      int q = i >> 3;
      int qs = (q & ~7) | ((q ^ (q >> 3)) & 7);
      int p = (qs << 3) | (i & 7);
      *(short4v*)&wfsH[p] = *(const short4v*)hh;
      *(short4v*)&wfsM[p] = *(const short4v*)mm;
      *(short4v*)&wfsL[p] = *(const short4v*)ll;
    }

#pragma unroll
    for (int i = 0; i < 2; ++i) { acc1[i][0] = (f32x4){0,0,0,0}; acc1[i][1] = (f32x4){0,0,0,0}; }

    __syncthreads();                               // wfs ready

    // gemm1 (r15 exact): X = A(wf) x Wf, K=256, B streamed from L2
    for (int kc = 0; kc < 8; ++kc) {
      short8 Ah[2], Am[2], Al[2];
#pragma unroll
      for (int mt = 0; mt < 2; ++mt) {
        int frame = (mt << 4) + (lane & 15);
        int q = (frame << 3) + (kc << 2) + (lane >> 4);
        int qs = (q & ~7) | ((q ^ (q >> 3)) & 7);
        Ah[mt] = *(const short8*)&wfsH[qs << 3];
        Am[mt] = *(const short8*)&wfsM[qs << 3];
        Al[mt] = *(const short8*)&wfsL[qs << 3];
      }
#pragma unroll
      for (int nt = 0; nt < 2; ++nt) {
        int ntg = (wv << 1) + nt;
        size_t off = (((size_t)((kc << 4) + ntg) << 6) + lane) << 3;
        short8 bh = *(const short8*)(WfH + off);
        short8 bm = *(const short8*)(WfM + off);
        short8 bl = *(const short8*)(WfL + off);
        __builtin_amdgcn_s_setprio(1);
#pragma unroll
        for (int mt = 0; mt < 2; ++mt) {
          MFMA6(acc1[mt][nt], Ah[mt], Am[mt], Al[mt], bh, bm, bl)
        }
        __builtin_amdgcn_s_setprio(0);
      }
    }
  }

  // ---- kb pipeline: tr-dump -> phase-modify -> S-chunk -> gemm2 partial ----
  for (int kb = 0; kb < 4; ++kb) {
    int pofs = (kb & 1) * 6144;

    if (!FIRST && (wv >> 1) == kb) {               // owning waves dump acc slab
      int q = wv & 1;
#pragma unroll
      for (int mt = 0; mt < 2; ++mt)
#pragma unroll
        for (int nt = 0; nt < 2; ++nt) {
          int cl = (q << 5) + (nt << 4) + (lane & 15);
#pragma unroll
          for (int r = 0; r < 4; ++r) {
            int row = (mt << 4) + ((lane >> 4) << 2) + r;
            tr[row * 65 + cl] = acc1[mt][nt][r];
          }
        }
    }
    __syncthreads();                               // tr ready (also: all waves
                                                   // finished gemm2(kb-1) reads)
    if (tid < 256) {                               // producer: 4 waves
      int row = tid >> 3, c8 = tid & 7;
      int srow = fgl + row;
      float4 mg4 = *(const float4*)&mag[((size_t)srow << 7) + (kb << 5) + (c8 << 2)];
      short reh[4] __attribute__((aligned(8))), rem[4] __attribute__((aligned(8))),
            rel[4] __attribute__((aligned(8))), imh[4] __attribute__((aligned(8))),
            imm[4] __attribute__((aligned(8))), iml[4] __attribute__((aligned(8)));
#pragma unroll
      for (int e = 0; e < 4; ++e) {
        float mg = ((const float*)&mg4)[e];
        float ore, oim;
        if (FIRST) { ore = mg; oim = 0.f; }        // S0 = (mag, 0)
        else {
          float re = tr[row * 65 + (c8 << 3) + 2 * e];
          float im = tr[row * 65 + (c8 << 3) + 2 * e + 1];
          float s2 = re * re + im * im;
          if (s2 == 0.f) { ore = mg; oim = 0.f; }  // angle(0)=0
          else { float rr = mg * rsqrtf(s2); ore = re * rr; oim = im * rr; }
        }
        split3(ore, &reh[e], &rem[e], &rel[e]);
        split3(oim, &imh[e], &imm[e], &iml[e]);
      }
      int cc = c8 >> 1, half = (c8 & 1) << 2;
      int sre = (cc ^ row ^ (row >> 3)) & 7;
      int sim = ((4 + cc) ^ row ^ (row >> 3)) & 7;
      int are = (row << 6) + (sre << 3) + half;
      int aim = (row << 6) + (sim << 3) + half;
      *(short4v*)&Sc[pofs + are]        = *(const short4v*)reh;
      *(short4v*)&Sc[pofs + aim]        = *(const short4v*)imh;
      *(short4v*)&Sc[pofs + 2048 + are] = *(const short4v*)rem;
      *(short4v*)&Sc[pofs + 2048 + aim] = *(const short4v*)imm;
      *(short4v*)&Sc[pofs + 4096 + are] = *(const short4v*)rel;
      *(short4v*)&Sc[pofs + 4096 + aim] = *(const short4v*)iml;
    }
    __syncthreads();                               // S-chunk ready; tr free

    // gemm2 partial: kc = kb (same k-order as r13/r15 -> bit-identical)
    {
      size_t flat = (((size_t)((kb << 3) + wv) << 6) + lane) << 3;
      short8 ciH = *(const short8*)(CI + flat);
      short8 ciM = *(const short8*)(CI + 16384 + flat);
      short8 ciL = *(const short8*)(CI + 32768 + flat);
      short8 siH = *(const short8*)(SI + flat);
      short8 siM = *(const short8*)(SI + 16384 + flat);
      short8 siL = *(const short8*)(SI + 32768 + flat);
      short8 ReH[2], ReM[2], ReL[2], ImH[2], ImM[2], ImL[2];
#pragma unroll
      for (int mt = 0; mt < 2; ++mt) {
        int row = (mt << 4) + (lane & 15);
        int cr = lane >> 4;
        int ar = (row << 6) + (((cr ^ row ^ (row >> 3)) & 7) << 3);
        int ai = (row << 6) + ((((4 + cr) ^ row ^ (row >> 3)) & 7) << 3);
        ReH[mt] = *(const short8*)&Sc[pofs + ar];
        ImH[mt] = *(const short8*)&Sc[pofs + ai];
        ReM[mt] = *(const short8*)&Sc[pofs + 2048 + ar];
        ImM[mt] = *(const short8*)&Sc[pofs + 2048 + ai];
        ReL[mt] = *(const short8*)&Sc[pofs + 4096 + ar];
        ImL[mt] = *(const short8*)&Sc[pofs + 4096 + ai];
      }
      __builtin_amdgcn_s_setprio(1);
#pragma unroll
      for (int mt = 0; mt < 2; ++mt) {
        MFMA6(aC[mt], ReH[mt], ReM[mt], ReL[mt], ciH, ciM, ciL)
        MFMA6(aS[mt], ImH[mt], ImM[mt], ImL[mt], siH, siM, siL)
      }
      __builtin_amdgcn_s_setprio(0);
    }
  }

  // unfold (r15 exact): fr[n]=swin[n](C+S_), fr[254-n]=swin[254-n](C-S_)
  {
    int n = (wv << 4) + (lane & 15);               // 0..127
    float swn = swin[n];
    float swp = swin[254 - n];
    float* FRo = FRdst + ((size_t)b << 16) + ((size_t)f0 << 8);
#pragma unroll
    for (int mt = 0; mt < 2; ++mt)
#pragma unroll
      for (int r = 0; r < 4; ++r) {
        int row = (mt << 4) + ((lane >> 4) << 2) + r;
        float C = aC[mt][r], S_ = aS[mt][r];
        FRo[((size_t)row << 8) + n] = swn * (C + S_);
        if (n >= 1 && n <= 126) FRo[((size_t)row << 8) + 254 - n] = swp * (C - S_);
        if (n == 0) { FRo[((size_t)row << 8) + 254] = 0.f; FRo[((size_t)row << 8) + 255] = 0.f; }
      }
  }
}

// ------------------------------------------------- reductions (OA fused) ----
__global__ void redmax_k(const float* __restrict__ FR, unsigned* __restrict__ gmax) {
  __shared__ float red[16];
  int b = blockIdx.x;
  const float* FRb = FR + ((size_t)b << 16);
  float v = 0.f;
  for (int t = threadIdx.x; t < OUTL; t += 1024) {
    int f_hi = t >> 6; if (f_hi > NFRM - 1) f_hi = NFRM - 1;
    int f_lo = (t >= NFFT) ? (((t - NFFT) >> 6) + 1) : 0;
    float s = 0.f;
    for (int f = f_lo; f <= f_hi; ++f) s += FRb[(f << 8) + t - (f << 6)];
    v = fmaxf(v, fabsf(s));
  }
#pragma unroll
  for (int o = 32; o > 0; o >>= 1) v = fmaxf(v, __shfl_xor(v, o, 64));
  if ((threadIdx.x & 63) == 0) red[threadIdx.x >> 6] = v;
  __syncthreads();
  if (threadIdx.x < 16) {
    v = red[threadIdx.x];
#pragma unroll
    for (int o = 8; o > 0; o >>= 1) v = fmaxf(v, __shfl_xor(v, o, 16));
    if (threadIdx.x == 0) atomicMax(gmax, __float_as_uint(v));
  }
}

__global__ void out_k(const float* __restrict__ FR, const unsigned* __restrict__ gmax,
                      float* __restrict__ out) {
  int b = blockIdx.y, t = blockIdx.x * 256 + threadIdx.x;   // t < 16384
  const float* FRb = FR + ((size_t)b << 16);
  int f_hi = t >> 6; if (f_hi > NFRM - 1) f_hi = NFRM - 1;
  int f_lo = (t >= NFFT) ? (((t - NFFT) >> 6) + 1) : 0;
  float s = 0.f;
  for (int f = f_lo; f <= f_hi; ++f) s += FRb[(f << 8) + t - (f << 6)];
  float g = __uint_as_float(*gmax);
  out[(size_t)b * AUD + t] = s / g;
}

// ---------------------------------------------------------------- launch ----
extern "C" void kernel_launch(void* const* d_in, const int* in_sizes, int n_in,
                              void* d_out, int out_size, void* d_ws, size_t ws_size,
                              hipStream_t stream) {
  const float* x = (const float*)d_in[0];

  float* FR0 = (float*)d_ws;                       // 8,388,608 f
  float* FR1 = FR0 + 8388608;                      // 8,388,608 f
  float* mag = FR1 + 8388608;                      // 4,194,304 f
  short* WfH = (short*)(mag + 4194304);            // 65536 sh each
  short* WfM = WfH + 65536;
  short* WfL = WfM + 65536;
  short* CI  = WfL + 65536;                        // 49152 sh each
  short* SI  = CI + 49152;
  float* swin = (float*)(SI + 49152);              // 256 f
  unsigned* gmax = (unsigned*)(swin + 256);        // ~84.7 MB total

  mag_k<<<16384, 256, 0, stream>>>(x, mag);
  tables_k<<<256, 256, 0, stream>>>(WfH, WfM, WfL, CI, SI, swin, gmax);

  // initial istft of (mag, 0) -> FR0
  iter_k<1><<<1024, 512, 0, stream>>>(FR1, FR0, mag, swin, WfH, WfM, WfL, CI, SI);

  float* bufs[2] = {FR0, FR1};
  for (int it = 0; it < GL_ITERS; ++it) {
    iter_k<0><<<1024, 512, 0, stream>>>(bufs[it & 1], bufs[(it + 1) & 1], mag, swin,
                                        WfH, WfM, WfL, CI, SI);
  }
  // 50 even -> final waveform frames in FR0

  redmax_k<<<B_SZ, 1024, 0, stream>>>(FR0, gmax);
  out_k<<<dim3(64, B_SZ), 256, 0, stream>>>(FR0, gmax, (float*)d_out);
}

// Round 17
// 2216.462 us; speedup vs baseline: 1.2640x; 1.2640x over previous
//
#include <hip/hip_runtime.h>
#include <math.h>

// Griffin-Lim inversion, fused bf16-3-term MFMA, M-tile=32, half-folded
// (r13/r15 validated math, bit-identical values), LDS-SLIM edition:
//   - wfs aliases into Y (dead after gemm1; barrier separates)
//   - epilogue via shfl_xor(1) re/im pairing (r10-validated, commutative-
//     equal to r15's tr-bounce) -> no tr scratch at all
// LDS 66 -> 48 KB => 3 blocks/CU (24 waves).  gemm1 K=256 unfolded;
// gemm2 folded n<->254-n, two K=128 half-GEMMs + fp32 unfold with swin.

#define B_SZ 128
#define NFRM 256
#define BINS 128
#define NFFT 254
#define OUTL 16574
#define AUD  16384
#define GL_ITERS 50
#define MAXV 69.37411499023438f
#define PI2f 6.2831853071795864f

typedef __attribute__((ext_vector_type(8))) short short8;
typedef __attribute__((ext_vector_type(4))) short short4v;
typedef __attribute__((ext_vector_type(4))) float f32x4;

__device__ __forceinline__ unsigned short f2bf(float f) {     // RNE f32->bf16
  unsigned u = __float_as_uint(f);
  return (unsigned short)((u + 0x7FFFu + ((u >> 16) & 1u)) >> 16);
}
__device__ __forceinline__ float bf2f(unsigned short h) {
  return __uint_as_float(((unsigned)h) << 16);
}
__device__ __forceinline__ void split3(float v, short* h, short* m, short* l) {
  unsigned short hh = f2bf(v);
  float r1 = v - bf2f(hh);
  unsigned short mm = f2bf(r1);
  float r2 = r1 - bf2f(mm);
  *h = (short)hh; *m = (short)mm; *l = (short)f2bf(r2);
}
// 16B chunk c of row r -> slot (c&~7)|((c^r^(r>>3))&7)  (bijective per 8-group)
__device__ __forceinline__ int slotf(int c, int row) {
  return (c & ~7) | ((c ^ row ^ (row >> 3)) & 7);
}

#define MFMA6(ACC, AH, AM, AL, BH, BM, BL)                                   \
  ACC = __builtin_amdgcn_mfma_f32_16x16x32_bf16(AH, BL, ACC, 0, 0, 0);       \
  ACC = __builtin_amdgcn_mfma_f32_16x16x32_bf16(AM, BM, ACC, 0, 0, 0);       \
  ACC = __builtin_amdgcn_mfma_f32_16x16x32_bf16(AL, BH, ACC, 0, 0, 0);       \
  ACC = __builtin_amdgcn_mfma_f32_16x16x32_bf16(AH, BM, ACC, 0, 0, 0);       \
  ACC = __builtin_amdgcn_mfma_f32_16x16x32_bf16(AM, BH, ACC, 0, 0, 0);       \
  ACC = __builtin_amdgcn_mfma_f32_16x16x32_bf16(AH, BH, ACC, 0, 0, 0);

// ---------------------------------------------------------------- tables ----
__global__ void tables_k(short* __restrict__ WfH, short* __restrict__ WfM,
                         short* __restrict__ WfL, short* __restrict__ CI,
                         short* __restrict__ SI, float* __restrict__ swin,
                         unsigned* __restrict__ gmax) {
  int tid = blockIdx.x * blockDim.x + threadIdx.x;
  if (tid == 0) *gmax = 0u;
  if (tid < 256) {
    float v = 0.f;
    if (tid < NFFT) {
      float wn = 0.5f - 0.5f * cosf(PI2f * (float)tid / (float)NFFT);
      float d = 0.f;
      int p = tid & 63;
      for (int q = 0; q < 4; ++q) {
        int nn = p + 64 * q;
        if (nn < NFFT) { float w = 0.5f - 0.5f * cosf(PI2f * (float)nn / (float)NFFT); d += w * w; }
      }
      v = wn / d;
    }
    swin[tid] = v;
  }
  if (tid < 65536) {
    int j = tid & 7, l = (tid >> 3) & 63, nt = (tid >> 9) & 15, kc = tid >> 13;
    int krow = kc * 32 + ((l >> 4) << 3) + j;        // sample n 0..255
    int ncol = (nt << 4) + (l & 15);                 // spec col 0..255
    float v1 = 0.f;
    if (krow < NFFT) {
      int kk = ncol >> 1;
      int m = (kk * krow) % NFFT;
      float ang = PI2f * (float)m / (float)NFFT;
      float wn = 0.5f - 0.5f * cosf(PI2f * (float)krow / (float)NFFT);
      v1 = wn * ((ncol & 1) ? -sinf(ang) : cosf(ang));
    }
    split3(v1, &WfH[tid], &WfM[tid], &WfL[tid]);
  }
  if (tid < 16384) {
    int j = tid & 7, l = (tid >> 3) & 63;
    int krow = (tid >> 12) * 32 + ((l >> 4) << 3) + j;   // bin k 0..127
    int ncol = (((tid >> 9) & 7) << 4) + (l & 15);       // sample n 0..127
    int m = (krow * ncol) % NFFT;
    float ang = PI2f * (float)m / (float)NFFT;
    float sc = ((krow == 0 || krow == BINS - 1) ? 1.f : 2.f) / (float)NFFT;
    split3(sc * cosf(ang), &CI[tid], &CI[16384 + tid], &CI[32768 + tid]);
    split3(-sc * sinf(ang), &SI[tid], &SI[16384 + tid], &SI[32768 + tid]);
  }
}

// ------------------------------------------------------------------- mag ----
__global__ void mag_k(const float* __restrict__ x, float* __restrict__ mag) {
  int i = blockIdx.x * 256 + threadIdx.x;          // 4194304 exact
  mag[i] = expf(5.f * (x[i] - 1.f)) * MAXV;
}

// ------------------------------------------------------ fused GL iteration --
// Block (XCD-swizzled) = (batch b, 32 frames from f0). 512 threads, 8 waves.
// Y (48 KB): Sre {H,M,L} at 0/4096/8192, Sim {H,M,L} at 12288/16384/20480,
// each [32 rows][128 bins] slotf-swizzled.  wfs (6720 sh) ALIASES Y[0..]
// during OA+gemm1 (dead before S is written; barrier separates).
template <int FIRST>
__global__ __launch_bounds__(512) void iter_k(
    const float* __restrict__ FRsrc, float* __restrict__ FRdst,
    const float* __restrict__ mag, const float* __restrict__ swin,
    const short* __restrict__ WfH, const short* __restrict__ WfM,
    const short* __restrict__ WfL,
    const short* __restrict__ CI, const short* __restrict__ SI) {
  __shared__ __align__(16) short Y[24576];         // 48 KB total
  short* wfsH = Y;                                 // alias: 2240 shorts each
  short* wfsM = Y + 2240;
  short* wfsL = Y + 4480;

  int o = blockIdx.x;
  int blk = ((o & 7) << 7) + (o >> 3);             // bijective (1024 % 8 == 0)
  int b = blk >> 3, f0 = (blk & 7) << 5;
  int tid = threadIdx.x, lane = tid & 63, wv = tid >> 6;
  int fgl = b * NFRM + f0;

  if (FIRST) {
    // S0 = (mag, 0): Sre = split3(mag), Sim = 0
    int row = tid >> 4, q = tid & 15;              // row 0..31, bin-octet 0..15
    int srow = fgl + row;
    float4 m0 = *(const float4*)&mag[((size_t)srow << 7) + (q << 3)];
    float4 m1 = *(const float4*)&mag[((size_t)srow << 7) + (q << 3) + 4];
    float mv[8] = {m0.x, m0.y, m0.z, m0.w, m1.x, m1.y, m1.z, m1.w};
    short h[8] __attribute__((aligned(16))), m[8] __attribute__((aligned(16))),
          l[8] __attribute__((aligned(16))), z[8] __attribute__((aligned(16)));
#pragma unroll
    for (int e = 0; e < 8; ++e) { split3(mv[e], &h[e], &m[e], &l[e]); z[e] = 0; }
    int off = (row << 7) + (slotf(q, row) << 3);
    *(short8*)&Y[off]         = *(const short8*)h;
    *(short8*)&Y[4096 + off]  = *(const short8*)m;
    *(short8*)&Y[8192 + off]  = *(const short8*)l;
    *(short8*)&Y[12288 + off] = *(const short8*)z;
    *(short8*)&Y[16384 + off] = *(const short8*)z;
    *(short8*)&Y[20480 + off] = *(const short8*)z;
  } else {
    const float* FRb = FRsrc + ((size_t)b << 16);
    // vectorized fused overlap-add -> split3 -> swizzled wfs (r15 exact)
    for (int i4 = tid; i4 < 560; i4 += 512) {
      int i = i4 << 2;
      int t = (f0 << 6) + i;
      int ft = t >> 6, cb = t & 63;
      float4 s = make_float4(0.f, 0.f, 0.f, 0.f);
#pragma unroll
      for (int d = 3; d >= 0; --d) {               // ascending f; extras exact 0
        int f = ft - d;
        if (f >= 0 && f <= 255) {
          float4 v = *(const float4*)&FRb[(f << 8) + cb + (d << 6)];
          s.x += v.x; s.y += v.y; s.z += v.z; s.w += v.w;
        }
      }
      if (i == 2236) { s.z = 0.f; s.w = 0.f; }     // pad samples 2238/2239
      short hh[4] __attribute__((aligned(8))), mm[4] __attribute__((aligned(8))),
            ll[4] __attribute__((aligned(8)));
      split3(s.x, &hh[0], &mm[0], &ll[0]);
      split3(s.y, &hh[1], &mm[1], &ll[1]);
      split3(s.z, &hh[2], &mm[2], &ll[2]);
      split3(s.w, &hh[3], &mm[3], &ll[3]);
      int q = i >> 3;
      int qs = (q & ~7) | ((q ^ (q >> 3)) & 7);
      int p = (qs << 3) | (i & 7);
      *(short4v*)&wfsH[p] = *(const short4v*)hh;
      *(short4v*)&wfsM[p] = *(const short4v*)mm;
      *(short4v*)&wfsL[p] = *(const short4v*)ll;
    }

    f32x4 acc1[2][2];
#pragma unroll
    for (int i = 0; i < 2; ++i) { acc1[i][0] = (f32x4){0,0,0,0}; acc1[i][1] = (f32x4){0,0,0,0}; }

    __syncthreads();                               // wfs ready

    // gemm1 (r15 exact): X = A(wf) x Wf, K=256, B streamed from L2
    for (int kc = 0; kc < 8; ++kc) {
      short8 Ah[2], Am[2], Al[2];
#pragma unroll
      for (int mt = 0; mt < 2; ++mt) {
        int frame = (mt << 4) + (lane & 15);
        int q = (frame << 3) + (kc << 2) + (lane >> 4);
        int qs = (q & ~7) | ((q ^ (q >> 3)) & 7);
        Ah[mt] = *(const short8*)&wfsH[qs << 3];
        Am[mt] = *(const short8*)&wfsM[qs << 3];
        Al[mt] = *(const short8*)&wfsL[qs << 3];
      }
#pragma unroll
      for (int nt = 0; nt < 2; ++nt) {
        int ntg = (wv << 1) + nt;
        size_t off = (((size_t)((kc << 4) + ntg) << 6) + lane) << 3;
        short8 bh = *(const short8*)(WfH + off);
        short8 bm = *(const short8*)(WfM + off);
        short8 bl = *(const short8*)(WfL + off);
        __builtin_amdgcn_s_setprio(1);
#pragma unroll
        for (int mt = 0; mt < 2; ++mt) {
          MFMA6(acc1[mt][nt], Ah[mt], Am[mt], Al[mt], bh, bm, bl)
        }
        __builtin_amdgcn_s_setprio(0);
      }
    }

    __syncthreads();                               // wfs dead -> Y free for S

    // epilogue: shfl re/im pairing (bit-identical to r15's tr-bounce):
    // s2 = re^2+im^2 (IEEE add commutes), rr = mg*rsqrt(s2), o = v*rr.
#pragma unroll
    for (int mt = 0; mt < 2; ++mt)
#pragma unroll
      for (int nt = 0; nt < 2; ++nt) {
        int col = (((wv << 1) + nt) << 4) | (lane & 15);
        int bin = col >> 1;
        int base = (col & 1) ? 12288 : 0;          // Sim : Sre
#pragma unroll
        for (int r = 0; r < 4; ++r) {
          int row = (mt << 4) + ((lane >> 4) << 2) + r;
          float v = acc1[mt][nt][r];
          float sq = v * v;
          float s2 = sq + __shfl_xor(sq, 1, 64);   // partner = re/im mate
          float mg = mag[((size_t)(fgl + row) << 7) + bin];
          float o;
          if (s2 == 0.f) o = (col & 1) ? 0.f : mg; // angle(0)=0
          else { float rr = mg * rsqrtf(s2); o = v * rr; }
          short oh, om, ol;
          split3(o, &oh, &om, &ol);
          int addr = (row << 7) + (slotf(bin >> 3, row) << 3) + (bin & 7);
          Y[base + addr] = oh;
          Y[base + 4096 + addr] = om;
          Y[base + 8192 + addr] = ol;
        }
      }
  }

  f32x4 aC[2], aS[2];
#pragma unroll
  for (int i = 0; i < 2; ++i) { aC[i] = (f32x4){0,0,0,0}; aS[i] = (f32x4){0,0,0,0}; }

  __syncthreads();                                 // Sre/Sim ready

  // gemm2 (folded, r15 exact): C = Sre x CI, S_ = Sim x SI, K=128 each
  for (int kc = 0; kc < 4; ++kc) {
    short8 ReH[2], ReM[2], ReL[2], ImH[2], ImM[2], ImL[2];
#pragma unroll
    for (int mt = 0; mt < 2; ++mt) {
      int rl = (mt << 4) + (lane & 15);
      int c = (kc << 2) + (lane >> 4);
      int off = (rl << 7) + (slotf(c, rl) << 3);
      ReH[mt] = *(const short8*)&Y[off];
      ReM[mt] = *(const short8*)&Y[4096 + off];
      ReL[mt] = *(const short8*)&Y[8192 + off];
      ImH[mt] = *(const short8*)&Y[12288 + off];
      ImM[mt] = *(const short8*)&Y[16384 + off];
      ImL[mt] = *(const short8*)&Y[20480 + off];
    }
    size_t flat = (((size_t)((kc << 3) + wv) << 6) + lane) << 3;
    short8 ch = *(const short8*)(CI + flat);
    short8 cm = *(const short8*)(CI + 16384 + flat);
    short8 cl = *(const short8*)(CI + 32768 + flat);
    short8 sh = *(const short8*)(SI + flat);
    short8 sm = *(const short8*)(SI + 16384 + flat);
    short8 sl = *(const short8*)(SI + 32768 + flat);
    __builtin_amdgcn_s_setprio(1);
#pragma unroll
    for (int mt = 0; mt < 2; ++mt) {
      MFMA6(aC[mt], ReH[mt], ReM[mt], ReL[mt], ch, cm, cl)
      MFMA6(aS[mt], ImH[mt], ImM[mt], ImL[mt], sh, sm, sl)
    }
    __builtin_amdgcn_s_setprio(0);
  }

  // unfold (r15 exact): fr[n]=swin[n](C+S_), fr[254-n]=swin[254-n](C-S_)
  {
    int n = (wv << 4) + (lane & 15);               // 0..127
    float swn = swin[n];
    float swp = swin[254 - n];
    float* FRo = FRdst + ((size_t)b << 16) + ((size_t)f0 << 8);
#pragma unroll
    for (int mt = 0; mt < 2; ++mt)
#pragma unroll
      for (int r = 0; r < 4; ++r) {
        int row = (mt << 4) + ((lane >> 4) << 2) + r;
        float C = aC[mt][r], S_ = aS[mt][r];
        FRo[((size_t)row << 8) + n] = swn * (C + S_);
        if (n >= 1 && n <= 126) FRo[((size_t)row << 8) + 254 - n] = swp * (C - S_);
        if (n == 0) { FRo[((size_t)row << 8) + 254] = 0.f; FRo[((size_t)row << 8) + 255] = 0.f; }
      }
  }
}

// ------------------------------------------------- reductions (OA fused) ----
__global__ void redmax_k(const float* __restrict__ FR, unsigned* __restrict__ gmax) {
  __shared__ float red[16];
  int b = blockIdx.x;
  const float* FRb = FR + ((size_t)b << 16);
  float v = 0.f;
  for (int t = threadIdx.x; t < OUTL; t += 1024) {
    int f_hi = t >> 6; if (f_hi > NFRM - 1) f_hi = NFRM - 1;
    int f_lo = (t >= NFFT) ? (((t - NFFT) >> 6) + 1) : 0;
    float s = 0.f;
    for (int f = f_lo; f <= f_hi; ++f) s += FRb[(f << 8) + t - (f << 6)];
    v = fmaxf(v, fabsf(s));
  }
#pragma unroll
  for (int o = 32; o > 0; o >>= 1) v = fmaxf(v, __shfl_xor(v, o, 64));
  if ((threadIdx.x & 63) == 0) red[threadIdx.x >> 6] = v;
  __syncthreads();
  if (threadIdx.x < 16) {
    v = red[threadIdx.x];
#pragma unroll
    for (int o = 8; o > 0; o >>= 1) v = fmaxf(v, __shfl_xor(v, o, 16));
    if (threadIdx.x == 0) atomicMax(gmax, __float_as_uint(v));
  }
}

__global__ void out_k(const float* __restrict__ FR, const unsigned* __restrict__ gmax,
                      float* __restrict__ out) {
  int b = blockIdx.y, t = blockIdx.x * 256 + threadIdx.x;   // t < 16384
  const float* FRb = FR + ((size_t)b << 16);
  int f_hi = t >> 6; if (f_hi > NFRM - 1) f_hi = NFRM - 1;
  int f_lo = (t >= NFFT) ? (((t - NFFT) >> 6) + 1) : 0;
  float s = 0.f;
  for (int f = f_lo; f <= f_hi; ++f) s += FRb[(f << 8) + t - (f << 6)];
  float g = __uint_as_float(*gmax);
  out[(size_t)b * AUD + t] = s / g;
}

// ---------------------------------------------------------------- launch ----
extern "C" void kernel_launch(void* const* d_in, const int* in_sizes, int n_in,
                              void* d_out, int out_size, void* d_ws, size_t ws_size,
                              hipStream_t stream) {
  const float* x = (const float*)d_in[0];

  float* FR0 = (float*)d_ws;                       // 8,388,608 f
  float* FR1 = FR0 + 8388608;                      // 8,388,608 f
  float* mag = FR1 + 8388608;                      // 4,194,304 f
  short* WfH = (short*)(mag + 4194304);            // 65536 sh each
  short* WfM = WfH + 65536;
  short* WfL = WfM + 65536;
  short* CI  = WfL + 65536;                        // 49152 sh each
  short* SI  = CI + 49152;
  float* swin = (float*)(SI + 49152);              // 256 f
  unsigned* gmax = (unsigned*)(swin + 256);        // ~84.7 MB total

  mag_k<<<16384, 256, 0, stream>>>(x, mag);
  tables_k<<<256, 256, 0, stream>>>(WfH, WfM, WfL, CI, SI, swin, gmax);

  // initial istft of (mag, 0) -> FR0
  iter_k<1><<<1024, 512, 0, stream>>>(FR1, FR0, mag, swin, WfH, WfM, WfL, CI, SI);

  float* bufs[2] = {FR0, FR1};
  for (int it = 0; it < GL_ITERS; ++it) {
    iter_k<0><<<1024, 512, 0, stream>>>(bufs[it & 1], bufs[(it + 1) & 1], mag, swin,
                                        WfH, WfM, WfL, CI, SI);
  }
  // 50 even -> final waveform frames in FR0

  redmax_k<<<B_SZ, 1024, 0, stream>>>(FR0, gmax);
  out_k<<<dim3(64, B_SZ), 256, 0, stream>>>(FR0, gmax, (float*)d_out);
}

// Round 19
// 2104.739 us; speedup vs baseline: 1.3311x; 1.0531x over previous
//
#include <hip/hip_runtime.h>
#include <math.h>

// Griffin-Lim inversion, fused bf16-3-term MFMA, M-tile=32, HALF-FOLDED
// (r13/r15 validated math) + s_setprio around MFMA clusters + XCD-aware
// bijective blockIdx swizzle.  gemm1 (STFT): K=256 unfolded, interleaved
// spec cols.  gemm2 (iSTFT): folded n<->254-n, two K=128 half-GEMMs + fp32
// unfold with swin.  This is the round-15 kernel restored verbatim
// (best validated state: 2.112 ms, absmax 0.006836).

#define B_SZ 128
#define NFRM 256
#define BINS 128
#define NFFT 254
#define OUTL 16574
#define AUD  16384
#define GL_ITERS 50
#define MAXV 69.37411499023438f
#define PI2f 6.2831853071795864f

typedef __attribute__((ext_vector_type(8))) short short8;
typedef __attribute__((ext_vector_type(4))) short short4v;
typedef __attribute__((ext_vector_type(4))) float f32x4;

__device__ __forceinline__ unsigned short f2bf(float f) {     // RNE f32->bf16
  unsigned u = __float_as_uint(f);
  return (unsigned short)((u + 0x7FFFu + ((u >> 16) & 1u)) >> 16);
}
__device__ __forceinline__ float bf2f(unsigned short h) {
  return __uint_as_float(((unsigned)h) << 16);
}
__device__ __forceinline__ void split3(float v, short* h, short* m, short* l) {
  unsigned short hh = f2bf(v);
  float r1 = v - bf2f(hh);
  unsigned short mm = f2bf(r1);
  float r2 = r1 - bf2f(mm);
  *h = (short)hh; *m = (short)mm; *l = (short)f2bf(r2);
}
// 16B chunk c of row r -> slot (c&~7)|((c^r^(r>>3))&7)  (bijective per 8-group)
__device__ __forceinline__ int slotf(int c, int row) {
  return (c & ~7) | ((c ^ row ^ (row >> 3)) & 7);
}

#define MFMA6(ACC, AH, AM, AL, BH, BM, BL)                                   \
  ACC = __builtin_amdgcn_mfma_f32_16x16x32_bf16(AH, BL, ACC, 0, 0, 0);       \
  ACC = __builtin_amdgcn_mfma_f32_16x16x32_bf16(AM, BM, ACC, 0, 0, 0);       \
  ACC = __builtin_amdgcn_mfma_f32_16x16x32_bf16(AL, BH, ACC, 0, 0, 0);       \
  ACC = __builtin_amdgcn_mfma_f32_16x16x32_bf16(AH, BM, ACC, 0, 0, 0);       \
  ACC = __builtin_amdgcn_mfma_f32_16x16x32_bf16(AM, BH, ACC, 0, 0, 0);       \
  ACC = __builtin_amdgcn_mfma_f32_16x16x32_bf16(AH, BH, ACC, 0, 0, 0);

// ---------------------------------------------------------------- tables ----
__global__ void tables_k(short* __restrict__ WfH, short* __restrict__ WfM,
                         short* __restrict__ WfL, short* __restrict__ CI,
                         short* __restrict__ SI, float* __restrict__ swin,
                         unsigned* __restrict__ gmax) {
  int tid = blockIdx.x * blockDim.x + threadIdx.x;
  if (tid == 0) *gmax = 0u;
  if (tid < 256) {
    float v = 0.f;
    if (tid < NFFT) {
      float wn = 0.5f - 0.5f * cosf(PI2f * (float)tid / (float)NFFT);
      float d = 0.f;
      int p = tid & 63;
      for (int q = 0; q < 4; ++q) {
        int nn = p + 64 * q;
        if (nn < NFFT) { float w = 0.5f - 0.5f * cosf(PI2f * (float)nn / (float)NFFT); d += w * w; }
      }
      v = wn / d;
    }
    swin[tid] = v;
  }
  if (tid < 65536) {
    int j = tid & 7, l = (tid >> 3) & 63, nt = (tid >> 9) & 15, kc = tid >> 13;
    int krow = kc * 32 + ((l >> 4) << 3) + j;        // sample n 0..255
    int ncol = (nt << 4) + (l & 15);                 // spec col 0..255
    float v1 = 0.f;
    if (krow < NFFT) {
      int kk = ncol >> 1;
      int m = (kk * krow) % NFFT;
      float ang = PI2f * (float)m / (float)NFFT;
      float wn = 0.5f - 0.5f * cosf(PI2f * (float)krow / (float)NFFT);
      v1 = wn * ((ncol & 1) ? -sinf(ang) : cosf(ang));
    }
    split3(v1, &WfH[tid], &WfM[tid], &WfL[tid]);
  }
  if (tid < 16384) {
    int j = tid & 7, l = (tid >> 3) & 63;
    int krow = (tid >> 12) * 32 + ((l >> 4) << 3) + j;   // bin k 0..127
    int ncol = (((tid >> 9) & 7) << 4) + (l & 15);       // sample n 0..127
    int m = (krow * ncol) % NFFT;
    float ang = PI2f * (float)m / (float)NFFT;
    float sc = ((krow == 0 || krow == BINS - 1) ? 1.f : 2.f) / (float)NFFT;
    split3(sc * cosf(ang), &CI[tid], &CI[16384 + tid], &CI[32768 + tid]);
    split3(-sc * sinf(ang), &SI[tid], &SI[16384 + tid], &SI[32768 + tid]);
  }
}

// ------------------------------------------------------------------- mag ----
__global__ void mag_k(const float* __restrict__ x, float* __restrict__ mag) {
  int i = blockIdx.x * 256 + threadIdx.x;          // 4194304 exact
  mag[i] = expf(5.f * (x[i] - 1.f)) * MAXV;
}

// ------------------------------------------------------ fused GL iteration --
// Block (after XCD swizzle) = (batch b, 32 frames from f0=(blk&7)*32).
// 512 threads, 8 waves.  Y (48 KB): Sre {H,M,L} 0/4096/8192, Sim {H,M,L}
// 12288/16384/20480, each [32 rows][128 bins] slotf-swizzled.
template <int FIRST>
__global__ __launch_bounds__(512) void iter_k(
    const float* __restrict__ FRsrc, float* __restrict__ FRdst,
    const float* __restrict__ mag, const float* __restrict__ swin,
    const short* __restrict__ WfH, const short* __restrict__ WfM,
    const short* __restrict__ WfL,
    const short* __restrict__ CI, const short* __restrict__ SI) {
  __shared__ __align__(16) short Y[24576];         // 48 KB (Sre/Sim)
  __shared__ __align__(16) char scratch[16896];    // wfs | trA/trB
  short* wfsH = (short*)scratch;                   // 2240 shorts each
  short* wfsM = wfsH + 2240;
  short* wfsL = wfsM + 2240;
  float* trA = (float*)scratch;                    // 16 x 132 f32 (cols 8c+0..3)
  float* trB = trA + 2112;                         // 16 x 132 f32 (cols 8c+4..7)

  // T1: bijective XCD swizzle (1024 % 8 == 0): same-batch blocks co-XCD.
  int o = blockIdx.x;
  int blk = ((o & 7) << 7) + (o >> 3);
  int b = blk >> 3, f0 = (blk & 7) << 5;
  int tid = threadIdx.x, lane = tid & 63, wv = tid >> 6;
  int fgl = b * NFRM + f0;

  if (FIRST) {
    // S0 = (mag, 0): Sre = split3(mag), Sim = 0
    int row = tid >> 4, q = tid & 15;              // row 0..31, bin-octet 0..15
    int srow = fgl + row;
    float4 m0 = *(const float4*)&mag[((size_t)srow << 7) + (q << 3)];
    float4 m1 = *(const float4*)&mag[((size_t)srow << 7) + (q << 3) + 4];
    float mv[8] = {m0.x, m0.y, m0.z, m0.w, m1.x, m1.y, m1.z, m1.w};
    short h[8] __attribute__((aligned(16))), m[8] __attribute__((aligned(16))),
          l[8] __attribute__((aligned(16))), z[8] __attribute__((aligned(16)));
#pragma unroll
    for (int e = 0; e < 8; ++e) { split3(mv[e], &h[e], &m[e], &l[e]); z[e] = 0; }
    int off = (row << 7) + (slotf(q, row) << 3);
    *(short8*)&Y[off]         = *(const short8*)h;
    *(short8*)&Y[4096 + off]  = *(const short8*)m;
    *(short8*)&Y[8192 + off]  = *(const short8*)l;
    *(short8*)&Y[12288 + off] = *(const short8*)z;
    *(short8*)&Y[16384 + off] = *(const short8*)z;
    *(short8*)&Y[20480 + off] = *(const short8*)z;
  } else {
    const float* FRb = FRsrc + ((size_t)b << 16);
    // vectorized fused overlap-add -> split3 -> swizzled wfs
    for (int i4 = tid; i4 < 560; i4 += 512) {
      int i = i4 << 2;
      int t = (f0 << 6) + i;
      int ft = t >> 6, cb = t & 63;
      float4 s = make_float4(0.f, 0.f, 0.f, 0.f);
#pragma unroll
      for (int d = 3; d >= 0; --d) {               // ascending f; extras exact 0
        int f = ft - d;
        if (f >= 0 && f <= 255) {
          float4 v = *(const float4*)&FRb[(f << 8) + cb + (d << 6)];
          s.x += v.x; s.y += v.y; s.z += v.z; s.w += v.w;
        }
      }
      if (i == 2236) { s.z = 0.f; s.w = 0.f; }     // pad samples 2238/2239
      short hh[4] __attribute__((aligned(8))), mm[4] __attribute__((aligned(8))),
            ll[4] __attribute__((aligned(8)));
      split3(s.x, &hh[0], &mm[0], &ll[0]);
      split3(s.y, &hh[1], &mm[1], &ll[1]);
      split3(s.z, &hh[2], &mm[2], &ll[2]);
      split3(s.w, &hh[3], &mm[3], &ll[3]);
      int q = i >> 3;
      int qs = (q & ~7) | ((q ^ (q >> 3)) & 7);
      int p = (qs << 3) | (i & 7);
      *(short4v*)&wfsH[p] = *(const short4v*)hh;
      *(short4v*)&wfsM[p] = *(const short4v*)mm;
      *(short4v*)&wfsL[p] = *(const short4v*)ll;
    }

    f32x4 acc1[2][2];
#pragma unroll
    for (int i = 0; i < 2; ++i) { acc1[i][0] = (f32x4){0,0,0,0}; acc1[i][1] = (f32x4){0,0,0,0}; }

    __syncthreads();                               // wfs ready

    // gemm1: X = A(wf) x Wf, K=256, B streamed from L2
    for (int kc = 0; kc < 8; ++kc) {
      short8 Ah[2], Am[2], Al[2];
#pragma unroll
      for (int mt = 0; mt < 2; ++mt) {
        int frame = (mt << 4) + (lane & 15);
        int q = (frame << 3) + (kc << 2) + (lane >> 4);
        int qs = (q & ~7) | ((q ^ (q >> 3)) & 7);
        Ah[mt] = *(const short8*)&wfsH[qs << 3];
        Am[mt] = *(const short8*)&wfsM[qs << 3];
        Al[mt] = *(const short8*)&wfsL[qs << 3];
      }
#pragma unroll
      for (int nt = 0; nt < 2; ++nt) {
        int ntg = (wv << 1) + nt;
        size_t off = (((size_t)((kc << 4) + ntg) << 6) + lane) << 3;
        short8 bh = *(const short8*)(WfH + off);
        short8 bm = *(const short8*)(WfM + off);
        short8 bl = *(const short8*)(WfL + off);
        __builtin_amdgcn_s_setprio(1);             // T5: favor MFMA cluster
#pragma unroll
        for (int mt = 0; mt < 2; ++mt) {
          MFMA6(acc1[mt][nt], Ah[mt], Am[mt], Al[mt], bh, bm, bl)
        }
        __builtin_amdgcn_s_setprio(0);
      }
    }

    // epilogue (tr-bounce): spec = mag*X/|X|; write Sre/Sim
    for (int mtg = 0; mtg < 2; ++mtg) {
      __syncthreads();                             // scratch free
#pragma unroll
      for (int nt = 0; nt < 2; ++nt) {
        int col = (((wv << 1) + nt) << 4) | (lane & 15);
        int cc = col >> 3, hb = (col >> 2) & 1, w = col & 3;
        float* th = hb ? trB : trA;
        int base = (cc << 2) + w;
#pragma unroll
        for (int r = 0; r < 4; ++r) {
          int row16 = ((lane >> 4) << 2) + r;
          th[row16 * 132 + base] = acc1[mtg][nt][r];
        }
      }
      __syncthreads();
      {
        int trow = tid >> 5;                       // 0..15
        int c = tid & 31;                          // 8-col chunk = 4 bins 4c..4c+3
        float4 va = *(const float4*)&trA[trow * 132 + (c << 2)];  // cols 8c+0..3
        float4 vb = *(const float4*)&trB[trow * 132 + (c << 2)];  // cols 8c+4..7
        int lrow = (mtg << 4) + trow;              // 0..31
        int srow = fgl + lrow;
        float4 xm = *(const float4*)&mag[((size_t)srow << 7) + (c << 2)];
        float vv[8] = {va.x, va.y, va.z, va.w, vb.x, vb.y, vb.z, vb.w};
        short reh[4] __attribute__((aligned(8))), rem[4] __attribute__((aligned(8))),
              rel[4] __attribute__((aligned(8))), imh[4] __attribute__((aligned(8))),
              imm[4] __attribute__((aligned(8))), iml[4] __attribute__((aligned(8)));
#pragma unroll
        for (int pq = 0; pq < 4; ++pq) {
          float mg = ((const float*)&xm)[pq];
          float re = vv[2 * pq], im = vv[2 * pq + 1];
          float s2 = re * re + im * im;
          float ore, oim;
          if (s2 == 0.f) { ore = mg; oim = 0.f; }  // angle(0)=0
          else { float rr = mg * rsqrtf(s2); ore = re * rr; oim = im * rr; }
          split3(ore, &reh[pq], &rem[pq], &rel[pq]);
          split3(oim, &imh[pq], &imm[pq], &iml[pq]);
        }
        int c2 = c >> 1, half = (c & 1) << 2;      // bins 4c..4c+3 in [32][128]
        int off2 = (lrow << 7) + (slotf(c2, lrow) << 3) + half;
        *(short4v*)&Y[off2]         = *(const short4v*)reh;
        *(short4v*)&Y[4096 + off2]  = *(const short4v*)rem;
        *(short4v*)&Y[8192 + off2]  = *(const short4v*)rel;
        *(short4v*)&Y[12288 + off2] = *(const short4v*)imh;
        *(short4v*)&Y[16384 + off2] = *(const short4v*)imm;
        *(short4v*)&Y[20480 + off2] = *(const short4v*)iml;
      }
    }
  }

  f32x4 aC[2], aS[2];
#pragma unroll
  for (int i = 0; i < 2; ++i) { aC[i] = (f32x4){0,0,0,0}; aS[i] = (f32x4){0,0,0,0}; }

  __syncthreads();                                 // Sre/Sim ready

  // gemm2 (folded): C = Sre x CI, S_ = Sim x SI, K=128 each; wave wv owns
  // sample tile ntg = wv (flat subtile index kc*8+wv).
  for (int kc = 0; kc < 4; ++kc) {
    short8 ReH[2], ReM[2], ReL[2], ImH[2], ImM[2], ImL[2];
#pragma unroll
    for (int mt = 0; mt < 2; ++mt) {
      int rl = (mt << 4) + (lane & 15);
      int c = (kc << 2) + (lane >> 4);
      int off = (rl << 7) + (slotf(c, rl) << 3);
      ReH[mt] = *(const short8*)&Y[off];
      ReM[mt] = *(const short8*)&Y[4096 + off];
      ReL[mt] = *(const short8*)&Y[8192 + off];
      ImH[mt] = *(const short8*)&Y[12288 + off];
      ImM[mt] = *(const short8*)&Y[16384 + off];
      ImL[mt] = *(const short8*)&Y[20480 + off];
    }
    size_t flat = (((size_t)((kc << 3) + wv) << 6) + lane) << 3;
    short8 ch = *(const short8*)(CI + flat);
    short8 cm = *(const short8*)(CI + 16384 + flat);
    short8 cl = *(const short8*)(CI + 32768 + flat);
    short8 sh = *(const short8*)(SI + flat);
    short8 sm = *(const short8*)(SI + 16384 + flat);
    short8 sl = *(const short8*)(SI + 32768 + flat);
    __builtin_amdgcn_s_setprio(1);                 // T5
#pragma unroll
    for (int mt = 0; mt < 2; ++mt) {
      MFMA6(aC[mt], ReH[mt], ReM[mt], ReL[mt], ch, cm, cl)
      MFMA6(aS[mt], ImH[mt], ImM[mt], ImL[mt], sh, sm, sl)
    }
    __builtin_amdgcn_s_setprio(0);
  }

  // unfold: fr[n]=swin[n](C+S_), fr[254-n]=swin[254-n](C-S_)
  {
    int n = (wv << 4) + (lane & 15);               // 0..127
    float swn = swin[n];
    float swp = swin[254 - n];
    float* FRo = FRdst + ((size_t)b << 16) + ((size_t)f0 << 8);
#pragma unroll
    for (int mt = 0; mt < 2; ++mt)
#pragma unroll
      for (int r = 0; r < 4; ++r) {
        int row = (mt << 4) + ((lane >> 4) << 2) + r;
        float C = aC[mt][r], S_ = aS[mt][r];
        FRo[((size_t)row << 8) + n] = swn * (C + S_);
        if (n >= 1 && n <= 126) FRo[((size_t)row << 8) + 254 - n] = swp * (C - S_);
        if (n == 0) { FRo[((size_t)row << 8) + 254] = 0.f; FRo[((size_t)row << 8) + 255] = 0.f; }
      }
  }
}

// ------------------------------------------------- reductions (OA fused) ----
__global__ void redmax_k(const float* __restrict__ FR, unsigned* __restrict__ gmax) {
  __shared__ float red[16];
  int b = blockIdx.x;
  const float* FRb = FR + ((size_t)b << 16);
  float v = 0.f;
  for (int t = threadIdx.x; t < OUTL; t += 1024) {
    int f_hi = t >> 6; if (f_hi > NFRM - 1) f_hi = NFRM - 1;
    int f_lo = (t >= NFFT) ? (((t - NFFT) >> 6) + 1) : 0;
    float s = 0.f;
    for (int f = f_lo; f <= f_hi; ++f) s += FRb[(f << 8) + t - (f << 6)];
    v = fmaxf(v, fabsf(s));
  }
#pragma unroll
  for (int o = 32; o > 0; o >>= 1) v = fmaxf(v, __shfl_xor(v, o, 64));
  if ((threadIdx.x & 63) == 0) red[threadIdx.x >> 6] = v;
  __syncthreads();
  if (threadIdx.x < 16) {
    v = red[threadIdx.x];
#pragma unroll
    for (int o = 8; o > 0; o >>= 1) v = fmaxf(v, __shfl_xor(v, o, 16));
    if (threadIdx.x == 0) atomicMax(gmax, __float_as_uint(v));
  }
}

__global__ void out_k(const float* __restrict__ FR, const unsigned* __restrict__ gmax,
                      float* __restrict__ out) {
  int b = blockIdx.y, t = blockIdx.x * 256 + threadIdx.x;   // t < 16384
  const float* FRb = FR + ((size_t)b << 16);
  int f_hi = t >> 6; if (f_hi > NFRM - 1) f_hi = NFRM - 1;
  int f_lo = (t >= NFFT) ? (((t - NFFT) >> 6) + 1) : 0;
  float s = 0.f;
  for (int f = f_lo; f <= f_hi; ++f) s += FRb[(f << 8) + t - (f << 6)];
  float g = __uint_as_float(*gmax);
  out[(size_t)b * AUD + t] = s / g;
}

// ---------------------------------------------------------------- launch ----
extern "C" void kernel_launch(void* const* d_in, const int* in_sizes, int n_in,
                              void* d_out, int out_size, void* d_ws, size_t ws_size,
                              hipStream_t stream) {
  const float* x = (const float*)d_in[0];

  float* FR0 = (float*)d_ws;                       // 8,388,608 f
  float* FR1 = FR0 + 8388608;                      // 8,388,608 f
  float* mag = FR1 + 8388608;                      // 4,194,304 f
  short* WfH = (short*)(mag + 4194304);            // 65536 sh each
  short* WfM = WfH + 65536;
  short* WfL = WfM + 65536;
  short* CI  = WfL + 65536;                        // 49152 sh each
  short* SI  = CI + 49152;
  float* swin = (float*)(SI + 49152);              // 256 f
  unsigned* gmax = (unsigned*)(swin + 256);        // ~84.7 MB total

  mag_k<<<16384, 256, 0, stream>>>(x, mag);
  tables_k<<<256, 256, 0, stream>>>(WfH, WfM, WfL, CI, SI, swin, gmax);

  // initial istft of (mag, 0) -> FR0
  iter_k<1><<<1024, 512, 0, stream>>>(FR1, FR0, mag, swin, WfH, WfM, WfL, CI, SI);

  float* bufs[2] = {FR0, FR1};
  for (int it = 0; it < GL_ITERS; ++it) {
    iter_k<0><<<1024, 512, 0, stream>>>(bufs[it & 1], bufs[(it + 1) & 1], mag, swin,
                                        WfH, WfM, WfL, CI, SI);
  }
  // 50 even -> final waveform frames in FR0

  redmax_k<<<B_SZ, 1024, 0, stream>>>(FR0, gmax);
  out_k<<<dim3(64, B_SZ), 256, 0, stream>>>(FR0, gmax, (float*)d_out);
}